// Round 6
// baseline (80.923 us; speedup 1.0000x reference)
//
#include <hip/hip_runtime.h>
#include <cstdint>
#include <cstddef>

// Problem constants (from reference setup_inputs)
#define NB 8
#define CH 256
#define DD 8
#define HH 16
#define WW 16
#define PP 2048          // D*H*W ; one z-slab = HH*WW = 256 voxels

// Workspace layout (bytes):
//   [0,     16384)   float partial[NB*8*16*4]  (per-wave numerator partials)
//   [16384, 17408)   float dpart[NB*8*4]       (per-wave denominator partials, cg==0)
#define OFF_DPART 16384

// Geometric z-window (verified absmax 0.0 in R2-R5): any positive pair
// satisfies |czq - czk| < 0.5*maxd (fp32 monotonicity: d2 >= dz^2, sqrt/div
// RN monotone). Window spans at most 2 k z-slabs. Returns first feasible zk
// clamped to [0, DD-2], or -1 if none.
__device__ __forceinline__ int z_window(float czq, float bdk, float k2, float maxd) {
    float lim = 0.500060f * maxd;
    int zk0 = -1;
    #pragma unroll
    for (int zk = 0; zk < DD; ++zk) {
        float czk = __fadd_rn(__fmul_rn(__fadd_rn((float)zk, 0.5f), bdk), k2);
        bool feas = fabsf(__fsub_rn(czq, czk)) < lim;
        if (feas && zk0 < 0) zk0 = zk;
    }
    if (zk0 > DD - 2) zk0 = DD - 2;
    return zk0;
}

// XOR swizzle for the voxel-major LDS layout: logical (cq, v) -> physical
// float4 slot. Breaks the 16-bank stride of the transpose-staging writes.
__device__ __forceinline__ int lds_slot(int cq, int v) {
    return cq * 512 + (v & ~3) + ((v & 3) ^ ((v >> 2) & 3));
}

// Fused kernel: block = (cg, zq, n), 1024 blocks = 4/CU. Stages the 2
// feasible k z-slabs (16 ch x 512 p') into LDS in VOXEL-MAJOR channel-quad
// layout (in-register 4x4 transpose, b128 writes, XOR-swizzled); each
// thread owns one q-voxel p, enumerates its <=18 candidates via per-dim
// index windows, classifies with a block-uniform d2 band (exact sqrt/div
// only inside the +-8e-7 band), gathers 4x ds_read_b128 per positive,
// dots with prefetched q registers, wave-shuffle-reduces to one global
// write per wave.
#define CC 16
__global__ __launch_bounds__(256) void fused_kernel(
    const float* __restrict__ q, const float* __restrict__ k,
    const float* __restrict__ coord_q, const float* __restrict__ coord_k,
    float* __restrict__ partial, float* __restrict__ dpart)
{
    __shared__ float4 klds[4 * 512];   // 32 KB

    int t  = threadIdx.x;
    int wv = t >> 6;
    int lane = t & 63;
    int cg = blockIdx.x;          // 16 channel groups
    int zq = blockIdx.y;          // 8 q z-slabs
    int n  = blockIdx.z;
    int flat = (n * 8 + zq) * 16 + cg;
    int c0 = cg * CC;

    // Block-uniform coord math (identical fp32 ops to the verified R5 code).
    const float* cq = coord_q + n * 6;
    const float* ck = coord_k + n * 6;
    float q0 = cq[0], q1 = cq[1], q2 = cq[2];
    float k0 = ck[0], k1 = ck[1], k2 = ck[2];
    float bwq = __fdiv_rn(__fsub_rn(cq[3], q0), (float)WW);
    float bhq = __fdiv_rn(__fsub_rn(cq[4], q1), (float)HH);
    float bdq = __fdiv_rn(__fsub_rn(cq[5], q2), (float)DD);
    float bwk = __fdiv_rn(__fsub_rn(ck[3], k0), (float)WW);
    float bhk = __fdiv_rn(__fsub_rn(ck[4], k1), (float)HH);
    float bdk = __fdiv_rn(__fsub_rn(ck[5], k2), (float)DD);
    float diagq = __fsqrt_rn(__fadd_rn(__fadd_rn(__fmul_rn(bwq, bwq), __fmul_rn(bhq, bhq)),
                                       __fmul_rn(bdq, bdq)));
    float diagk = __fsqrt_rn(__fadd_rn(__fadd_rn(__fmul_rn(bwk, bwk), __fmul_rn(bhk, bhk)),
                                       __fmul_rn(bdk, bdk)));
    float maxd = fmaxf(diagq, diagk);
    float cqz = __fadd_rn(__fmul_rn(__fadd_rn((float)zq, 0.5f), bdq), q2);

    int zk0 = z_window(cqz, bdk, k2, maxd);
    if (zk0 < 0) {                 // no feasible k-slab for this q z-slab
        if (lane == 0) {
            partial[flat * 4 + wv] = 0.0f;
            if (cg == 0) dpart[(n * 8 + zq) * 4 + wv] = 0.0f;
        }
        return;
    }
    int base_p = zk0 << 8;

    // Prefetch this thread's q values (coalesced per c).
    int p = (zq << 8) + t;
    float qv[CC];
    {
        const float* qcol = q + ((size_t)(n * CH + c0)) * PP + p;
        #pragma unroll
        for (int c = 0; c < CC; ++c)
            qv[c] = qcol[(size_t)c * PP];
    }

    // Stage k[n, c0..c0+15, base_p..base_p+511] -> LDS, voxel-major
    // channel-quads via in-register 4x4 transpose. Global loads coalesced
    // (128 lanes x 16B contiguous per (jj,r)); LDS writes b128 swizzled.
    {
        const float* ksrc = k + ((size_t)(n * CH + c0)) * PP + base_p;
        int vq = t & 127;           // voxel quad: voxels 4vq..4vq+3
        int jb = t >> 7;            // 0 or 1
        #pragma unroll
        for (int jj = 0; jj < 4; ++jj) {
            if ((jj & 1) != jb) continue;   // this thread handles jj = jb, jb+2
            float a0[4], a1[4], a2[4], a3[4];
            *(float4*)a0 = *(const float4*)(ksrc + (size_t)(4 * jj + 0) * PP + 4 * vq);
            *(float4*)a1 = *(const float4*)(ksrc + (size_t)(4 * jj + 1) * PP + 4 * vq);
            *(float4*)a2 = *(const float4*)(ksrc + (size_t)(4 * jj + 2) * PP + 4 * vq);
            *(float4*)a3 = *(const float4*)(ksrc + (size_t)(4 * jj + 3) * PP + 4 * vq);
            #pragma unroll
            for (int s = 0; s < 4; ++s) {
                float4 o;
                o.x = a0[s]; o.y = a1[s]; o.z = a2[s]; o.w = a3[s];
                klds[lds_slot(jj, 4 * vq + s)] = o;
            }
        }
    }
    __syncthreads();

    // This thread's q-voxel center (exact fp32 chain).
    int ix = t & 15, iy = (t >> 4) & 15;
    float cqx = __fadd_rn(__fmul_rn(__fadd_rn((float)ix, 0.5f), bwq), q0);
    float cqy = __fadd_rn(__fmul_rn(__fadd_rn((float)iy, 0.5f), bhq), q1);

    // Conservative per-dim index windows (reciprocal-mul; margins absorb
    // recip error). Enumerated candidates get the exact-band test, so
    // over-inclusion is harmless (verified absmax 0.0 in R4/R5).
    float lim = 0.500060f * maxd;
    float ibwk = __frcp_rn(bwk), ibhk = __frcp_rn(bhk);
    float tx = (cqx - k0) * ibwk - 0.5f;
    float ty = (cqy - k1) * ibhk - 0.5f;
    float rx = lim * ibwk + 0.031f;
    float ry = lim * ibhk + 0.031f;
    int jx0 = (int)ceilf(tx - rx);  if (jx0 < 0) jx0 = 0;
    int jx1 = (int)floorf(tx + rx); if (jx1 > WW - 1) jx1 = WW - 1;
    int jy0 = (int)ceilf(ty - ry);  if (jy0 < 0) jy0 = 0;
    int jy1 = (int)floorf(ty + ry); if (jy1 > HH - 1) jy1 = HH - 1;

    // Block-uniform d2 classification band. RN sqrt/div are monotone, so:
    //   d2 < T_lo  => fdiv(fsqrt(d2),maxd) <= 0.5*sqrt(1-8e-7)*(1+1.2e-7) < 0.5
    //   d2 >= T_hi => dist >= 0.5*sqrt(1+8e-7)*(1-1.2e-7) > 0.5
    // Only the ~+-8e-7 relative band needs the exact sqrt/div (raref).
    float half_maxd = 0.5f * maxd;           // exact (pow2 scale)
    float T    = half_maxd * half_maxd;
    float T_lo = T * (1.0f - 8e-7f);
    float T_hi = T * (1.0f + 8e-7f);

    float4 s4[4];
    #pragma unroll
    for (int c = 0; c < 4; ++c) s4[c] = make_float4(0.f, 0.f, 0.f, 0.f);
    int cnt = 0;

    for (int dzI = 0; dzI < 2; ++dzI) {
        int jz = zk0 + dzI;
        float ckz = __fadd_rn(__fmul_rn(__fadd_rn((float)jz, 0.5f), bdk), k2);
        float dz  = __fsub_rn(cqz, ckz);
        float dz2 = __fmul_rn(dz, dz);
        for (int jy = jy0; jy <= jy1; ++jy) {
            float cky = __fadd_rn(__fmul_rn(__fadd_rn((float)jy, 0.5f), bhk), k1);
            float dy  = __fsub_rn(cqy, cky);
            float dy2 = __fmul_rn(dy, dy);
            for (int jx = jx0; jx <= jx1; ++jx) {
                float ckx = __fadd_rn(__fmul_rn(__fadd_rn((float)jx, 0.5f), bwk), k0);
                float dx  = __fsub_rn(cqx, ckx);
                float dx2 = __fmul_rn(dx, dx);
                float d2  = __fadd_rn(__fadd_rn(dx2, dy2), dz2);
                bool pos = d2 < T_lo;
                if (d2 >= T_lo && d2 < T_hi) {   // boundary band: exact test
                    float dist = __fdiv_rn(__fsqrt_rn(d2), maxd);
                    pos = dist < 0.5f;
                }
                if (pos) {
                    ++cnt;
                    int idx = (dzI << 8) + (jy << 4) + jx;
                    int vlo = (idx & ~3) + ((idx & 3) ^ ((idx >> 2) & 3));
                    #pragma unroll
                    for (int c = 0; c < 4; ++c) {
                        float4 kv = klds[c * 512 + vlo];
                        s4[c].x += kv.x; s4[c].y += kv.y;
                        s4[c].z += kv.z; s4[c].w += kv.w;
                    }
                }
            }
        }
    }

    float acc = 0.0f;
    #pragma unroll
    for (int c = 0; c < 4; ++c) {
        acc += qv[4 * c + 0] * s4[c].x;
        acc += qv[4 * c + 1] * s4[c].y;
        acc += qv[4 * c + 2] * s4[c].z;
        acc += qv[4 * c + 3] * s4[c].w;
    }

    // Wave-shuffle reduction (no syncthreads), one write per wave.
    int ci = cnt;
    #pragma unroll
    for (int off = 32; off > 0; off >>= 1) {
        acc += __shfl_down(acc, off, 64);
        ci  += __shfl_down(ci, off, 64);
    }
    if (lane == 0) {
        partial[flat * 4 + wv] = acc;
        if (cg == 0) dpart[(n * 8 + zq) * 4 + wv] = (float)ci;
    }
}

// Final: one wave per batch sums 512 numerator partials + 32 denominator
// partials; thread 0 combines.
__global__ __launch_bounds__(512) void final_kernel(const float* __restrict__ partial,
                                                    const float* __restrict__ dpart,
                                                    float* __restrict__ out)
{
    __shared__ float numsh[NB];
    __shared__ float densh[NB];
    int t = threadIdx.x;
    int n = t >> 6, lane = t & 63;

    float sp = 0.0f;
    #pragma unroll
    for (int i = 0; i < 8; ++i)
        sp += partial[n * 512 + i * 64 + lane];
    float sc = (lane < 32) ? dpart[n * 32 + lane] : 0.0f;
    #pragma unroll
    for (int off = 32; off > 0; off >>= 1) {
        sp += __shfl_down(sp, off, 64);
        sc += __shfl_down(sc, off, 64);
    }
    if (lane == 0) { numsh[n] = sp; densh[n] = sc; }
    __syncthreads();
    if (t == 0) {
        float r = 0.0f;
        for (int i = 0; i < NB; ++i)
            r += numsh[i] / (densh[i] + 1e-6f);
        out[0] = -2.0f * (r / (float)NB);
    }
}

extern "C" void kernel_launch(void* const* d_in, const int* in_sizes, int n_in,
                              void* d_out, int out_size, void* d_ws, size_t ws_size,
                              hipStream_t stream) {
    const float* q       = (const float*)d_in[0];
    const float* k       = (const float*)d_in[1];
    const float* coord_q = (const float*)d_in[2];
    const float* coord_k = (const float*)d_in[3];
    float* out = (float*)d_out;

    char* w = (char*)d_ws;
    float* partial = (float*)w;
    float* dpart   = (float*)(w + OFF_DPART);

    fused_kernel<<<dim3(CH / CC, DD, NB), 256, 0, stream>>>(q, k, coord_q, coord_k,
                                                            partial, dpart);
    final_kernel<<<1, 512, 0, stream>>>(partial, dpart, out);
}